// Round 1
// baseline (1234.962 us; speedup 1.0000x reference)
//
#include <hip/hip_runtime.h>

// Decision-tree traversal, binary features packed to bits on the fly.
//
// x:      [N, W] int32, values strictly in {0,1}  (N=250000, W=784 -> 784 MB)
// choices:[N_NODES] int32 split-feature per node (256 KB, L2-resident)
// preds:  [N_NODES] float32 leaf prediction (0.0/1.0)
// depth:  scalar int32 on device (=15)
// out:    [N] int32 (bool semantics 0/1)
//
// Old kernel: 15 dependent 4B random gathers/row from HBM -> latency +
// line-granularity bound (~0.3-0.5 TB/s effective). New kernel:
//   Phase 1: wave-ballot bit-pack. Each wave streams 64 rows with coalesced
//            256B reads (lane L -> feature seg*64+L), __ballot packs 64
//            features per instruction into LDS word-major [WPR][256].
//            784 MB sequential stream -> HBM-BW bound.
//   Phase 2: per-thread traversal entirely from LDS (bank = tid&31,
//            conflict-free) + hot choices table (L1/L2).
// LDS: 25 words * 256 threads * 4B = 25.6 KB/block.

template <int NSEG_C, int TAIL_C>
__global__ __launch_bounds__(256) void Tree_17867063951635_kernel(
    const int*   __restrict__ x,
    const int*   __restrict__ choices,
    const float* __restrict__ preds,
    const int*   __restrict__ depth_p,
    int*         __restrict__ out,
    int n, int w)
{
    extern __shared__ unsigned lds[];   // [WPR][256], word-major: lds[word*256 + row]

    const int tid  = threadIdx.x;
    const int lane = tid & 63;
    const int wid  = tid >> 6;                       // wave in block (0..3)
    const long long blockRow0 = (long long)blockIdx.x * 256;

    const int nseg = NSEG_C ? NSEG_C : (w >> 6);     // full 64-feature segments
    const int tail = NSEG_C ? TAIL_C : (w & 63);     // leftover features

    // ---------------- Phase 1: ballot bit-pack 256 rows into LDS ----------------
    // Wave `wid` packs block-local rows [wid*64, wid*64+64). For each 64-feature
    // segment: one coalesced 256B load, one ballot, lanes 0/1 store the two words.
    for (int rr = 0; rr < 64; ++rr) {
        const int r = (wid << 6) + rr;               // block-local row
        const long long grow = blockRow0 + r;        // global row (wave-uniform)
        if (grow < n) {
            const int* __restrict__ rowp = x + grow * (long long)w;
            #pragma unroll
            for (int seg = 0; seg < nseg; ++seg) {
                const int v = rowp[(seg << 6) + lane];          // coalesced 256B
                const unsigned long long m = __ballot(v != 0);  // 64 bits packed
                if (lane < 2)
                    lds[((seg << 1) + lane) * 256 + r] = (unsigned)(m >> (lane << 5));
            }
            if (tail) {
                const int v = (lane < tail) ? rowp[(nseg << 6) + lane] : 0;
                const unsigned long long m = __ballot(v != 0);
                if (lane < 2 && (lane << 5) < tail)
                    lds[((nseg << 1) + lane) * 256 + r] = (unsigned)(m >> (lane << 5));
            }
        }
    }
    __syncthreads();

    // ---------------- Phase 2: per-thread traversal from LDS ----------------
    const long long i = blockRow0 + tid;
    if (i < n) {
        const int depth = *depth_p;                  // uniform scalar
        int node = 0;
        for (int d = 0; d < depth; ++d) {
            const int c = choices[node];             // hot table, L1/L2
            // word-major layout: bank = tid & 31 -> conflict-free
            const unsigned bits = lds[(c >> 5) * 256 + tid];
            node = (node << 1) + (int)((bits >> (c & 31)) & 1u) + 1;
        }
        out[i] = (preds[node] != 0.0f) ? 1 : 0;      // bool as int32
    }
}

extern "C" void kernel_launch(void* const* d_in, const int* in_sizes, int n_in,
                              void* d_out, int out_size, void* d_ws, size_t ws_size,
                              hipStream_t stream) {
    const int*   x       = (const int*)d_in[0];
    const int*   choices = (const int*)d_in[1];
    const float* preds   = (const float*)d_in[2];
    const int*   depth_p = (const int*)d_in[3];
    int*         out     = (int*)d_out;

    const int n = out_size;                 // 250000 samples
    const int w = in_sizes[0] / n;          // 784 features

    const int block = 256;
    const int grid  = (n + block - 1) / block;
    const int wpr   = (w + 31) / 32;        // packed words per row (25)
    const size_t lds_bytes = (size_t)wpr * 256 * sizeof(unsigned);

    if (w == 784) {
        Tree_17867063951635_kernel<12, 16><<<grid, block, lds_bytes, stream>>>(
            x, choices, preds, depth_p, out, n, w);
    } else {
        Tree_17867063951635_kernel<0, 0><<<grid, block, lds_bytes, stream>>>(
            x, choices, preds, depth_p, out, n, w);
    }
}

// Round 2
// 1076.842 us; speedup vs baseline: 1.1468x; 1.1468x over previous
//
#include <hip/hip_runtime.h>

// Decision-tree traversal via two-kernel pipeline through workspace.
//
// x:      [N, W] int32, values strictly in {0,1}  (N=250000, W=784 -> 784 MB)
// choices:[N_NODES] int32 split-feature per node (256 KB, L2-hot)
// preds:  [N_NODES] float32 leaf prediction (0.0/1.0)
// depth:  scalar int32 on device (=15)
// out:    [N] int32 (bool semantics 0/1)
//
// Baseline (911 us): 15 dependent 4B random gathers/row from a 784 MB
// uncachable array -> line-granularity HBM bound (~0.4 TB/s effective).
// Round-1 fused pack+traverse (1235 us): packing parallelism was capped at
// 3908 waves with a serial 64-row loop per wave + LDS/barrier coupling.
//
// This version decouples:
//   Kernel A (pack): bit-pack x -> ws [N][25] uint32 (25 MB). One wave packs
//     4 rows -> 62,500 waves, zero LDS, coalesced 256B reads + __ballot.
//     Pure 784 MB stream -> HBM-BW bound (~130-170 us).
//   Kernel B (traverse): same chain as baseline, but gathers hit the 25 MB
//     packed matrix: L3-resident, each thread's row is 100 B (2 lines) so
//     repeat gathers are L1/L2 hits. Latency-bound, fully occupancy-hidden.

// ---------------------------------------------------------------- kernel A
template <int NSEG_C, int TAIL_C>
__global__ __launch_bounds__(256) void pack_kernel(
    const int* __restrict__ x,
    unsigned*  __restrict__ packed,
    int n, int w, int nseg_rt, int tail_rt, int wpr)
{
    const int  gtid = blockIdx.x * blockDim.x + threadIdx.x;
    const int  wave = gtid >> 6;
    const int  lane = gtid & 63;
    const long long row0 = (long long)wave * 4;          // 4 rows per wave

    const int nseg = NSEG_C ? NSEG_C : nseg_rt;
    const int tail = NSEG_C ? TAIL_C : tail_rt;

    #pragma unroll
    for (int rr = 0; rr < 4; ++rr) {
        const long long r = row0 + rr;
        if (r >= n) return;                              // wave-uniform
        const int* __restrict__ rowp = x + r * (long long)w;
        unsigned*  __restrict__ outp = packed + r * (long long)wpr;

        #pragma unroll
        for (int seg = 0; seg < nseg; ++seg) {
            const int v = rowp[(seg << 6) + lane];       // coalesced 256B
            const unsigned long long m = __ballot(v != 0);
            if (lane < 2)
                outp[(seg << 1) + lane] = (unsigned)(m >> (lane << 5));
        }
        if (tail) {
            const int v = (lane < tail) ? rowp[(nseg << 6) + lane] : 0;
            const unsigned long long m = __ballot(v != 0);
            if (lane < 2 && (lane << 5) < tail)
                outp[(nseg << 1) + lane] = (unsigned)(m >> (lane << 5));
        }
    }
}

// ---------------------------------------------------------------- kernel B
__global__ __launch_bounds__(256) void traverse_kernel(
    const unsigned* __restrict__ packed,
    const int*      __restrict__ choices,
    const float*    __restrict__ preds,
    const int*      __restrict__ depth_p,
    int*            __restrict__ out,
    int n, int wpr)
{
    const int i = blockIdx.x * blockDim.x + threadIdx.x;
    if (i >= n) return;

    const unsigned* __restrict__ row = packed + (long long)i * wpr;
    const int depth = *depth_p;                          // uniform scalar

    int node = 0;
    for (int d = 0; d < depth; ++d) {
        const int c = choices[node];                     // hot tree table
        const unsigned bits = row[c >> 5];               // own 100B row: L1/L2 hit
        node = (node << 1) + (int)((bits >> (c & 31)) & 1u) + 1;
    }
    out[i] = (preds[node] != 0.0f) ? 1 : 0;              // bool as int32
}

// ------------------------------------------------- fallback (baseline 911us)
__global__ __launch_bounds__(256) void direct_kernel(
    const int*   __restrict__ x,
    const int*   __restrict__ choices,
    const float* __restrict__ preds,
    const int*   __restrict__ depth_p,
    int*         __restrict__ out,
    int n, int w)
{
    const int i = blockIdx.x * blockDim.x + threadIdx.x;
    if (i >= n) return;
    const int depth = *depth_p;
    const int* __restrict__ row = x + (long long)i * (long long)w;
    int node = 0;
    for (int d = 0; d < depth; ++d) {
        const int c   = choices[node];
        const int bit = row[c];
        node = node * 2 + bit + 1;
    }
    out[i] = (preds[node] != 0.0f) ? 1 : 0;
}

extern "C" void kernel_launch(void* const* d_in, const int* in_sizes, int n_in,
                              void* d_out, int out_size, void* d_ws, size_t ws_size,
                              hipStream_t stream) {
    const int*   x       = (const int*)d_in[0];
    const int*   choices = (const int*)d_in[1];
    const float* preds   = (const float*)d_in[2];
    const int*   depth_p = (const int*)d_in[3];
    int*         out     = (int*)d_out;

    const int n = out_size;                 // 250000 samples
    const int w = in_sizes[0] / n;          // 784 features

    const int wpr = (w + 31) / 32;          // packed words per row (25)
    const size_t need = (size_t)n * wpr * sizeof(unsigned);   // ~25 MB

    if (ws_size < need) {
        // workspace too small: proven direct kernel (baseline performance)
        const int block = 256;
        const int grid  = (n + block - 1) / block;
        direct_kernel<<<grid, block, 0, stream>>>(x, choices, preds, depth_p,
                                                  out, n, w);
        return;
    }

    unsigned* packed = (unsigned*)d_ws;

    // Kernel A: one wave packs 4 rows.
    {
        const int block = 256;                         // 4 waves/block
        const long long waves = ((long long)n + 3) / 4;
        const long long grid  = (waves + 3) / 4;       // 4 waves per block
        const int nseg = w >> 6, tail = w & 63;
        if (w == 784)
            pack_kernel<12, 16><<<dim3((unsigned)grid), block, 0, stream>>>(
                x, packed, n, w, nseg, tail, wpr);
        else
            pack_kernel<0, 0><<<dim3((unsigned)grid), block, 0, stream>>>(
                x, packed, n, w, nseg, tail, wpr);
    }

    // Kernel B: traversal against packed matrix (stream-ordered after A).
    {
        const int block = 256;
        const int grid  = (n + block - 1) / block;
        traverse_kernel<<<grid, block, 0, stream>>>(packed, choices, preds,
                                                    depth_p, out, n, wpr);
    }
}